// Round 4
// baseline (618.900 us; speedup 1.0000x reference)
//
#include <hip/hip_runtime.h>
#include <math.h>

#define NNODES 50000
#define NEDGES 800000
#define D 128
#define NPB 4            // nodes per fused block
#define ROWS (NPB * 9)   // 36 token rows
#define MT 3             // 48 rows incl. padding
#define TS 136           // tokS row stride (halfs): 272 B -> word stride 68 (mod 32 = 4)
#define KS 264           // kvS row stride (halfs): 528 B -> word stride 132 (mod 32 = 4)
#define OS 132           // oo row stride (floats): mod 32 = 4

typedef _Float16 half_t;
typedef half_t half8 __attribute__((ext_vector_type(8)));
typedef float floatx4 __attribute__((ext_vector_type(4)));

// ---------------- CSR build ----------------

__global__ __launch_bounds__(256) void count_both_kernel(const int* __restrict__ ei0,
                                                         const int* __restrict__ ei1,
                                                         int* __restrict__ cnt0,
                                                         int* __restrict__ cnt1) {
  const int gE = (NEDGES + 255) / 256;
  int b = blockIdx.x;
  const int* ei = (b < gE) ? ei0 : ei1;
  int* cnt = (b < gE) ? cnt0 : cnt1;
  int e = (b % gE) * 256 + threadIdx.x;
  if (e < NEDGES) atomicAdd(&cnt[ei[NEDGES + e]], 1);
}

// 2 blocks (one per edge set), 1024 threads. Thread-serial chunks of 49 + one block scan.
__global__ __launch_bounds__(1024) void scan_kernel(
    const int* __restrict__ cnt0, int* __restrict__ off0, int* __restrict__ cur0,
    const int* __restrict__ cnt1, int* __restrict__ off1, int* __restrict__ cur1) {
  const int* cnt = (blockIdx.x == 0) ? cnt0 : cnt1;
  int* off = (blockIdx.x == 0) ? off0 : off1;
  int* cur = (blockIdx.x == 0) ? cur0 : cur1;
  const int CHUNK = 49;  // 49*1024 >= 50000
  __shared__ int sm[1024];
  int tid = threadIdx.x;
  int base = tid * CHUNK;
  int local = 0;
  for (int i = 0; i < CHUNK; ++i) {
    int idx = base + i;
    if (idx < NNODES) local += cnt[idx];
  }
  sm[tid] = local;
  __syncthreads();
  for (int o = 1; o < 1024; o <<= 1) {
    int t = (tid >= o) ? sm[tid - o] : 0;
    __syncthreads();
    sm[tid] += t;
    __syncthreads();
  }
  int run = sm[tid] - local;  // exclusive prefix of this chunk
  for (int i = 0; i < CHUNK; ++i) {
    int idx = base + i;
    if (idx < NNODES) {
      off[idx] = run;
      cur[idx] = run;
      run += cnt[idx];
    }
  }
  if (tid == 1023) off[NNODES] = sm[1023];
}

__global__ __launch_bounds__(256) void scatter_both_kernel(const int* __restrict__ ei0,
                                                           const int* __restrict__ ei1,
                                                           int* __restrict__ cur0,
                                                           int* __restrict__ cur1,
                                                           int* __restrict__ list0,
                                                           int* __restrict__ list1) {
  const int gE = (NEDGES + 255) / 256;
  int b = blockIdx.x;
  const int* ei = (b < gE) ? ei0 : ei1;
  int* cur = (b < gE) ? cur0 : cur1;
  int* list = (b < gE) ? list0 : list1;
  int e = (b % gE) * 256 + threadIdx.x;
  if (e < NEDGES) {
    int s = ei[e];
    int d = ei[NEDGES + e];
    int pos = atomicAdd(&cur[d], 1);
    list[pos] = s;
  }
}

// ---------------- prep: weight swizzle (fp16 B-fragments) + x -> fp16 ----------------
// W chunk c = nt*4+ks holds 64 lanes x 8 half: lane l -> n = nt*16+(l&15),
// k = ks*32 + (l>>4)*8 + j. B-frag load = base + lane*16B (coalesced).

__global__ __launch_bounds__(256) void prep_kernel(const float* __restrict__ w_in,
                                                   const float* __restrict__ w_out,
                                                   const float* __restrict__ x,
                                                   half_t* __restrict__ w_swz,
                                                   half_t* __restrict__ wo_swz,
                                                   half_t* __restrict__ x16) {
  int slot = blockIdx.x * 256 + threadIdx.x;
  if (slot < 8192) {  // weight swizzle
    const float* src;
    half_t* dst;
    int c, l;
    if (slot < 96 * 64) {
      c = slot >> 6; l = slot & 63;
      src = w_in; dst = w_swz + (size_t)slot * 8;
    } else {
      int s2 = slot - 96 * 64;
      c = s2 >> 6; l = s2 & 63;
      src = w_out; dst = wo_swz + (size_t)s2 * 8;
    }
    int nt = c >> 2, ks = c & 3;
    int n = nt * 16 + (l & 15);
    int kb = ks * 32 + (l >> 4) * 8;
#pragma unroll
    for (int j = 0; j < 8; ++j) dst[j] = (half_t)src[n * 128 + kb + j];
  } else {
    int idx = slot - 8192;  // 4 floats each; 50000*128/4 = 1.6M slots
    if (idx < NNODES * D / 4) {
      float4 v = ((const float4*)x)[idx];
      union { half_t h[4]; uint2 u64; } p;
      p.h[0] = (half_t)v.x; p.h[1] = (half_t)v.y;
      p.h[2] = (half_t)v.z; p.h[3] = (half_t)v.w;
      ((uint2*)x16)[idx] = p.u64;
    }
  }
}

// ---------------- aggregation: wave per (node, edge-set), fp16 gather ----------------

__global__ __launch_bounds__(256) void aggregate_kernel(
    const half_t* __restrict__ x16,
    const int* __restrict__ off0, const int* __restrict__ list0,
    const int* __restrict__ off1, const int* __restrict__ list1,
    half_t* __restrict__ tok) {
  const int tid = threadIdx.x;
  const int wv = tid >> 6, lane = tid & 63;
  const int node = blockIdx.x * 2 + (wv >> 1);
  const int set = wv & 1;
  const size_t tb = (size_t)node * 9 * 128;

  union U { uint u; half_t h[2]; };

  if (set == 0) {  // copy self token (row 0)
    uint u = ((const uint*)(x16 + (size_t)node * 128))[lane];
    ((uint*)(tok + tb))[lane] = u;
  }

  const int* off = set ? off1 : off0;
  const int* list = set ? list1 : list0;
  int s = off[node], e = off[node + 1];
  int cnt = e - s;

  float s0 = 0.f, s1 = 0.f;
  float mx0 = -INFINITY, mx1 = -INFINITY, mn0 = INFINITY, mn1 = INFINITY;
  int j = s;
  for (; j + 3 < e; j += 4) {
    int i0 = list[j], i1 = list[j + 1], i2 = list[j + 2], i3 = list[j + 3];
    U a, b, c, d;
    a.u = ((const uint*)(x16 + (size_t)i0 * 128))[lane];
    b.u = ((const uint*)(x16 + (size_t)i1 * 128))[lane];
    c.u = ((const uint*)(x16 + (size_t)i2 * 128))[lane];
    d.u = ((const uint*)(x16 + (size_t)i3 * 128))[lane];
    float a0 = (float)a.h[0], a1 = (float)a.h[1];
    float b0 = (float)b.h[0], b1 = (float)b.h[1];
    float c0 = (float)c.h[0], c1 = (float)c.h[1];
    float d0 = (float)d.h[0], d1 = (float)d.h[1];
    s0 += (a0 + b0) + (c0 + d0);
    s1 += (a1 + b1) + (c1 + d1);
    mx0 = fmaxf(mx0, fmaxf(fmaxf(a0, b0), fmaxf(c0, d0)));
    mx1 = fmaxf(mx1, fmaxf(fmaxf(a1, b1), fmaxf(c1, d1)));
    mn0 = fminf(mn0, fminf(fminf(a0, b0), fminf(c0, d0)));
    mn1 = fminf(mn1, fminf(fminf(a1, b1), fminf(c1, d1)));
  }
  for (; j < e; ++j) {
    U a;
    a.u = ((const uint*)(x16 + (size_t)list[j] * 128))[lane];
    float a0 = (float)a.h[0], a1 = (float)a.h[1];
    s0 += a0; s1 += a1;
    mx0 = fmaxf(mx0, a0); mx1 = fmaxf(mx1, a1);
    mn0 = fminf(mn0, a0); mn1 = fminf(mn1, a1);
  }
  if (cnt == 0) { mx0 = mx1 = mn0 = mn1 = 0.f; }
  float inv = 1.f / (float)(cnt > 1 ? cnt : 1);

  size_t b0r = tb + (size_t)(1 + 4 * set) * 128;
  U p;
  p.h[0] = (half_t)mx0; p.h[1] = (half_t)mx1;
  ((uint*)(tok + b0r))[lane] = p.u;
  p.h[0] = (half_t)mn0; p.h[1] = (half_t)mn1;
  ((uint*)(tok + b0r + 128))[lane] = p.u;
  p.h[0] = (half_t)s0; p.h[1] = (half_t)s1;
  ((uint*)(tok + b0r + 256))[lane] = p.u;
  p.h[0] = (half_t)(s0 * inv); p.h[1] = (half_t)(s1 * inv);
  ((uint*)(tok + b0r + 384))[lane] = p.u;
}

// ---------------- fused MFMA projection + attention + w_out + LN ----------------
// 4 nodes/block, 256 threads (4 waves), ~34 KB LDS -> 4 blocks/CU.

__global__ __launch_bounds__(256, 4) void fused_attn_kernel(
    const half_t* __restrict__ tok16,
    const half_t* __restrict__ w_swz, const half_t* __restrict__ wo_swz,
    const float* __restrict__ b_in, const float* __restrict__ b_out,
    const int* __restrict__ off0, const int* __restrict__ off1,
    const float* __restrict__ gamma, const float* __restrict__ beta,
    float* __restrict__ out) {
  __shared__ half_t tokS[48 * TS];   // 13056 B; later reused: o16 [16][TS] + oo fp32 [16][OS]
  __shared__ half_t kvS[ROWS * KS];  // 19008 B: cols 0-127 = k, 128-255 = v
  __shared__ half_t qS[NPB * TS];    // q of token 0 per node
  __shared__ float scS[NPB][4][9];
  __shared__ int cntS[NPB][2];

  const int tid = threadIdx.x;
  const int lane = tid & 63, wv = tid >> 6;
  const int quad = lane >> 4, l15 = lane & 15;

  // stage 36 token rows into padded tokS (+zero rows 36-47). 16 uint4 per row!
  {
    const uint4* src = (const uint4*)(tok16 + (size_t)blockIdx.x * ROWS * 128);
    for (int i = tid; i < 48 * 16; i += 256) {
      int row = i >> 4, c = i & 15;
      uint4 v = (row < ROWS) ? src[row * 16 + c] : make_uint4(0, 0, 0, 0);
      *(uint4*)(tokS + row * TS + c * 8) = v;
    }
  }
  if (tid < 2 * NPB) {
    int ln = tid >> 1, ss = tid & 1;
    int node = blockIdx.x * NPB + ln;
    const int* off = ss ? off1 : off0;
    cntS[ln][ss] = off[node + 1] - off[node];
  }
  __syncthreads();

  // GEMM1: C[48x384] = tok @ w_in^T. A hoisted in regs; B loaded once per (nt,ks).
  {
    half8 a[MT][4];
#pragma unroll
    for (int mt = 0; mt < MT; ++mt)
#pragma unroll
      for (int ks = 0; ks < 4; ++ks)
        a[mt][ks] = *(const half8*)(tokS + (mt * 16 + l15) * TS + ks * 32 + quad * 8);

    for (int ntb = 0; ntb < 6; ++ntb) {
      int nt = wv + ntb * 4;  // 24 n-tiles over 4 waves
      half8 b[4];
#pragma unroll
      for (int ks = 0; ks < 4; ++ks)
        b[ks] = *(const half8*)(w_swz + ((size_t)(nt * 4 + ks) * 64 + lane) * 8);
      int col = nt * 16 + l15;
      float bias = b_in[col];
#pragma unroll
      for (int mt = 0; mt < MT; ++mt) {
        floatx4 acc = {0.f, 0.f, 0.f, 0.f};
#pragma unroll
        for (int ks = 0; ks < 4; ++ks)
          acc = __builtin_amdgcn_mfma_f32_16x16x32_f16(a[mt][ks], b[ks], acc, 0, 0, 0);
#pragma unroll
        for (int r = 0; r < 4; ++r) {
          int row = mt * 16 + quad * 4 + r;
          if (row < ROWS) {
            float v = acc[r] + bias;
            if (col < 128) {
              if (row % 9 == 0) qS[(row / 9) * TS + col] = (half_t)v;
            } else {
              kvS[row * KS + (col - 128)] = (half_t)v;
            }
          }
        }
      }
    }
  }
  __syncthreads();

  // scores: wave wv = node; lane -> (h = lane>>4, t = lane&15), t<9 active
  {
    int h = lane >> 4, t = lane & 15;
    if (t < 9) {
      float sc;
      bool masked = (t >= 1) && ((t <= 4) ? (cntS[wv][0] == 0) : (cntS[wv][1] == 0));
      if (masked) {
        sc = -1e30f;
      } else {
        const half_t* qp = qS + wv * TS + h * 32;
        const half_t* kp = kvS + (wv * 9 + t) * KS + h * 32;
        float acc = 0.f;
#pragma unroll
        for (int d2 = 0; d2 < 32; ++d2) acc += (float)qp[d2] * (float)kp[d2];
        sc = acc * 0.17677669529663687f;  // 1/sqrt(32)
      }
      scS[wv][h][t] = sc;
    }
  }
  __syncthreads();

  if (lane < 4) {  // softmax per (node=wv, head=lane)
    int h = lane;
    float m = -INFINITY;
#pragma unroll
    for (int t = 0; t < 9; ++t) m = fmaxf(m, scS[wv][h][t]);
    float ev[9], sum = 0.f;
#pragma unroll
    for (int t = 0; t < 9; ++t) { ev[t] = __expf(scS[wv][h][t] - m); sum += ev[t]; }
    float inv = 1.f / sum;
#pragma unroll
    for (int t = 0; t < 9; ++t) scS[wv][h][t] = ev[t] * inv;
  }
  __syncthreads();

  // PV: o16[node][d] = sum_t attn * v ; also zero pad rows 4-15 (o16 aliases tokS)
  half_t* o16 = tokS;
  {
    for (int i = tid; i < 12 * TS / 2; i += 256)  // zero rows 4..15
      ((uint*)(o16 + 4 * TS))[i] = 0u;
#pragma unroll
    for (int u = 0; u < 2; ++u) {
      int d2 = lane + 64 * u;
      int h = d2 >> 5;
      float acc = 0.f;
#pragma unroll
      for (int t = 0; t < 9; ++t)
        acc += scS[wv][h][t] * (float)kvS[(wv * 9 + t) * KS + 128 + d2];
      o16[wv * TS + d2] = (half_t)acc;
    }
  }
  __syncthreads();

  // GEMM2: oo[16x128] = o16 @ w_out^T + b_out
  float* oo = (float*)(tokS + 16 * TS);
  {
    half8 a[4];
#pragma unroll
    for (int ks = 0; ks < 4; ++ks)
      a[ks] = *(const half8*)(o16 + l15 * TS + ks * 32 + quad * 8);
#pragma unroll
    for (int ntb = 0; ntb < 2; ++ntb) {
      int nt = wv + ntb * 4;
      half8 b[4];
#pragma unroll
      for (int ks = 0; ks < 4; ++ks)
        b[ks] = *(const half8*)(wo_swz + ((size_t)(nt * 4 + ks) * 64 + lane) * 8);
      floatx4 acc = {0.f, 0.f, 0.f, 0.f};
#pragma unroll
      for (int ks = 0; ks < 4; ++ks)
        acc = __builtin_amdgcn_mfma_f32_16x16x32_f16(a[ks], b[ks], acc, 0, 0, 0);
      int col = nt * 16 + l15;
      float bias = b_out[col];
#pragma unroll
      for (int r = 0; r < 4; ++r) {
        int row = quad * 4 + r;
        oo[row * OS + col] = acc[r] + bias;
      }
    }
  }
  __syncthreads();

  // LayerNorm per node (wave wv = node; lane covers 2 cols)
  {
    float v[2];
    float sum = 0.f, sq = 0.f;
#pragma unroll
    for (int u = 0; u < 2; ++u) {
      int c = lane + 64 * u;
      v[u] = oo[wv * OS + c];
      sum += v[u];
      sq += v[u] * v[u];
    }
#pragma unroll
    for (int m = 1; m < 64; m <<= 1) {
      sum += __shfl_xor(sum, m);
      sq += __shfl_xor(sq, m);
    }
    float mu = sum * (1.f / 128.f);
    float var = sq * (1.f / 128.f) - mu * mu;
    float rs = rsqrtf(var + 1e-5f);
    int node = blockIdx.x * NPB + wv;
#pragma unroll
    for (int u = 0; u < 2; ++u) {
      int c = lane + 64 * u;
      out[(size_t)node * 128 + c] = (v[u] - mu) * rs * gamma[c] + beta[c];
    }
  }
}

// ---------------- launch ----------------

extern "C" void kernel_launch(void* const* d_in, const int* in_sizes, int n_in,
                              void* d_out, int out_size, void* d_ws, size_t ws_size,
                              hipStream_t stream) {
  const float* x = (const float*)d_in[0];
  const int* ei0 = (const int*)d_in[1];
  const int* ei1 = (const int*)d_in[2];
  const float* w_in = (const float*)d_in[3];
  const float* b_in = (const float*)d_in[4];
  const float* w_out = (const float*)d_in[5];
  const float* b_out = (const float*)d_in[6];
  const float* gamma = (const float*)d_in[7];
  const float* beta = (const float*)d_in[8];
  float* out = (float*)d_out;

  char* wsB = (char*)d_ws;
  size_t off = 0;
  auto alloc_i = [&](size_t n) { int* p = (int*)(wsB + off); off += n * 4; return p; };
  int* cnt0 = alloc_i(NNODES);
  int* cnt1 = alloc_i(NNODES);
  int* off0 = alloc_i(NNODES + 1);
  int* off1 = alloc_i(NNODES + 1);
  int* cur0 = alloc_i(NNODES);
  int* cur1 = alloc_i(NNODES);
  int* list0 = alloc_i(NEDGES);
  int* list1 = alloc_i(NEDGES);
  off = (off + 15) & ~(size_t)15;
  half_t* w_swz = (half_t*)(wsB + off);  off += (size_t)96 * 64 * 8 * 2;
  half_t* wo_swz = (half_t*)(wsB + off); off += (size_t)32 * 64 * 8 * 2;
  half_t* x16 = (half_t*)(wsB + off);    off += (size_t)NNODES * 128 * 2;
  half_t* tok16 = (half_t*)(wsB + off);  off += (size_t)NNODES * 9 * 128 * 2;

  hipMemsetAsync(cnt0, 0, 2 * NNODES * sizeof(int), stream);

  const int gE = (NEDGES + 255) / 256;
  count_both_kernel<<<2 * gE, 256, 0, stream>>>(ei0, ei1, cnt0, cnt1);
  scan_kernel<<<2, 1024, 0, stream>>>(cnt0, off0, cur0, cnt1, off1, cur1);
  scatter_both_kernel<<<2 * gE, 256, 0, stream>>>(ei0, ei1, cur0, cur1, list0, list1);
  prep_kernel<<<(8192 + NNODES * D / 4 + 255) / 256, 256, 0, stream>>>(
      w_in, w_out, x, w_swz, wo_swz, x16);
  aggregate_kernel<<<NNODES / 2, 256, 0, stream>>>(x16, off0, list0, off1, list1, tok16);
  fused_attn_kernel<<<NNODES / NPB, 256, 0, stream>>>(tok16, w_swz, wo_swz, b_in, b_out,
                                                      off0, off1, gamma, beta, out);
}